// Round 1
// baseline (22605.812 us; speedup 1.0000x reference)
//
#include <hip/hip_runtime.h>

#define NN 50000
#define FF 16
#define TH 10
#define EE 800000
#define HH 64

__device__ __forceinline__ float ftanh(float x) {
  // tanh(x) = 1 - 2/(exp(2x)+1); exp->v_exp_f32, rcp->v_rcp_f32. inf/0 safe.
  float e = __expf(x + x);
  return 1.0f - 2.0f * __builtin_amdgcn_rcpf(e + 1.0f);
}

// ---------------- preprocessing ----------------

__global__ void count_kernel(const int* __restrict__ ei, int* __restrict__ counts) {
  int e = blockIdx.x * 256 + threadIdx.x;
  if (e < EE) atomicAdd(&counts[ei[EE + e]], 1);
}

__global__ void scan_kernel(const int* __restrict__ counts, int* __restrict__ row_ptr) {
  __shared__ int lds[1024];
  const int CH = (NN + 1023) / 1024;  // 49
  int t = threadIdx.x;
  int beg = t * CH, end = beg + CH;
  if (beg > NN) beg = NN;
  if (end > NN) end = NN;
  int s = 0;
  for (int i = beg; i < end; i++) s += counts[i];
  lds[t] = s;
  __syncthreads();
  for (int off = 1; off < 1024; off <<= 1) {
    int v = (t >= off) ? lds[t - off] : 0;
    __syncthreads();
    lds[t] += v;
    __syncthreads();
  }
  int run = lds[t] - s;  // exclusive prefix
  for (int i = beg; i < end; i++) { row_ptr[i] = run; run += counts[i]; }
  if (t == 1023) row_ptr[NN] = lds[1023];
}

__global__ void fill_kernel(const int* __restrict__ ei, const float* __restrict__ ea,
                            const int* __restrict__ row_ptr, int* __restrict__ cursor,
                            int* __restrict__ src_sorted, float* __restrict__ ea_sorted) {
  int e = blockIdx.x * 256 + threadIdx.x;
  if (e >= EE) return;
  int d = ei[EE + e];
  int pos = row_ptr[d] + atomicAdd(&cursor[d], 1);
  src_sorted[pos] = ei[e];
  ((float4*)ea_sorted)[pos] = ((const float4*)ea)[e];
}

__global__ void times_kernel(const float* __restrict__ t, float* __restrict__ dts,
                             float* __restrict__ tis) {
  int u = threadIdx.x;
  if (u >= 40) return;
  int iv = u >> 2, fr = u & 3;
  float dti = (t[iv + 1] - t[iv]) * 0.25f;
  dts[u] = dti;
  float t0 = t[iv] + (float)fr * dti;
  const float C[6] = {0.0f, 0.2f, 0.3f, 0.8f, (float)(8.0 / 9.0), 1.0f};
  for (int s = 0; s < 6; s++) tis[u * 6 + s] = t0 + C[s] * dti;
}

// aug_pre[n][j] = b1n[j] + sum_i aug[n][i] * W1n[32+i][j]   (176-dim aug)
__global__ __launch_bounds__(256) void augpre_kernel(
    const float* __restrict__ xh, const float* __restrict__ xm,
    const float* __restrict__ W1n, const float* __restrict__ b1n,
    float* __restrict__ aug_pre) {
  __shared__ float Wl[176 * 64];
  __shared__ float augl[4][176];
  for (int i = threadIdx.x; i < 176 * 64; i += 256) Wl[i] = W1n[32 * 64 + i];
  __syncthreads();
  int wv = threadIdx.x >> 6, j = threadIdx.x & 63;
  float bj = b1n[j];
  for (int base = blockIdx.x * 4; base < NN; base += gridDim.x * 4) {
    int n = base + wv;  // NN % 4 == 0, always valid
    if (j < 16) {
      int f = j;
      float xv[TH], mv[TH], summ = 0.f;
      #pragma unroll
      for (int tt = 0; tt < TH; tt++) {
        xv[tt] = xh[(tt * NN + n) * FF + f];
        mv[tt] = xm[tt * NN + n];
        summ += mv[tt];
      }
      float cnt = fmaxf(summ, 1.0f);
      float mean = 0.f;
      #pragma unroll
      for (int tt = 0; tt < TH; tt++) mean += xv[tt] * mv[tt];
      mean *= __builtin_amdgcn_rcpf(cnt);
      float var = 0.f;
      #pragma unroll
      for (int tt = 0; tt < TH; tt++) { float d = xv[tt] - mean; var += d * d * mv[tt]; }
      var *= __builtin_amdgcn_rcpf(cnt);
      #pragma unroll
      for (int tt = 0; tt < TH - 1; tt++)
        augl[wv][tt * 16 + f] = (xv[tt + 1] - xv[tt]) * (mv[tt + 1] * mv[tt]);
      augl[wv][144 + f] = mean;
      augl[wv][160 + f] = var;
    }
    __syncthreads();
    float acc = bj;
    #pragma unroll 8
    for (int i = 0; i < 176; i++) acc += augl[wv][i] * Wl[i * 64 + j];
    aug_pre[n * 64 + j] = acc;
    __syncthreads();
  }
}

// ---------------- vector field (one wave per node, lane = hidden unit) ----------------

__global__ __launch_bounds__(256) void vf_kernel(
    const float* __restrict__ xi, float* __restrict__ kout,
    const int* __restrict__ row_ptr, const int* __restrict__ srcs,
    const float* __restrict__ eas, const float* __restrict__ aug_pre,
    const float* __restrict__ tis, int tidx,
    const float* __restrict__ W1m, const float* __restrict__ b1m,
    const float* __restrict__ W2m, const float* __restrict__ b2m,
    const float* __restrict__ W1n, const float* __restrict__ W2n,
    const float* __restrict__ b2n) {
  __shared__ float ldsS[4][64];
  __shared__ float ldsA[4][16];
  int wv = threadIdx.x >> 6;
  int j = threadIdx.x & 63;
  int n = blockIdx.x * 4 + wv;
  int n_s = __builtin_amdgcn_readfirstlane(n);
  int g = j >> 4, kk = j & 15;

  // per-lane weight columns
  float Uc[16], Vc[16], Ec[4];
  #pragma unroll
  for (int i = 0; i < 16; i++) { Uc[i] = W1m[i * 64 + j]; Vc[i] = W1m[(16 + i) * 64 + j]; }
  #pragma unroll
  for (int i = 0; i < 4; i++) Ec[i] = W1m[(32 + i) * 64 + j];
  float b1 = b1m[j];
  float ti = tis[tidx];

  // x[dst] (wave-uniform -> scalar loads)
  const float4* xr = (const float4*)(xi + n_s * 16);
  float4 d0 = xr[0], d1 = xr[1], d2 = xr[2], d3 = xr[3];
  float xd[16] = {d0.x, d0.y, d0.z, d0.w, d1.x, d1.y, d1.z, d1.w,
                  d2.x, d2.y, d2.z, d2.w, d3.x, d3.y, d3.z, d3.w};

  float Qj = b1;
  #pragma unroll
  for (int i = 0; i < 16; i++) Qj += xd[i] * Vc[i];

  int e0 = __builtin_amdgcn_readfirstlane(row_ptr[n_s]);
  int e1 = __builtin_amdgcn_readfirstlane(row_ptr[n_s + 1]);
  float sj = 0.f;

  int e = e0;
  for (; e + 1 < e1; e += 2) {  // 2-wide to overlap SMEM latency
    int sp0 = __builtin_amdgcn_readfirstlane(srcs[e]);
    int sp1 = __builtin_amdgcn_readfirstlane(srcs[e + 1]);
    const float4* p0 = (const float4*)(xi + sp0 * 16);
    const float4* p1 = (const float4*)(xi + sp1 * 16);
    float4 a0 = p0[0], a1 = p0[1], a2 = p0[2], a3 = p0[3];
    float4 c0 = p1[0], c1 = p1[1], c2 = p1[2], c3 = p1[3];
    float4 eav0 = ((const float4*)eas)[e];
    float4 eav1 = ((const float4*)eas)[e + 1];
    float h0 = Qj, h1 = Qj;
    h0 += a0.x * Uc[0] + a0.y * Uc[1] + a0.z * Uc[2] + a0.w * Uc[3];
    h0 += a1.x * Uc[4] + a1.y * Uc[5] + a1.z * Uc[6] + a1.w * Uc[7];
    h0 += a2.x * Uc[8] + a2.y * Uc[9] + a2.z * Uc[10] + a2.w * Uc[11];
    h0 += a3.x * Uc[12] + a3.y * Uc[13] + a3.z * Uc[14] + a3.w * Uc[15];
    h0 += eav0.x * Ec[0] + eav0.y * Ec[1] + eav0.z * Ec[2] + eav0.w * Ec[3];
    h1 += c0.x * Uc[0] + c0.y * Uc[1] + c0.z * Uc[2] + c0.w * Uc[3];
    h1 += c1.x * Uc[4] + c1.y * Uc[5] + c1.z * Uc[6] + c1.w * Uc[7];
    h1 += c2.x * Uc[8] + c2.y * Uc[9] + c2.z * Uc[10] + c2.w * Uc[11];
    h1 += c3.x * Uc[12] + c3.y * Uc[13] + c3.z * Uc[14] + c3.w * Uc[15];
    h1 += eav1.x * Ec[0] + eav1.y * Ec[1] + eav1.z * Ec[2] + eav1.w * Ec[3];
    sj += ftanh(h0) + ftanh(h1);
  }
  if (e < e1) {
    int sp0 = __builtin_amdgcn_readfirstlane(srcs[e]);
    const float4* p0 = (const float4*)(xi + sp0 * 16);
    float4 a0 = p0[0], a1 = p0[1], a2 = p0[2], a3 = p0[3];
    float4 eav0 = ((const float4*)eas)[e];
    float h0 = Qj;
    h0 += a0.x * Uc[0] + a0.y * Uc[1] + a0.z * Uc[2] + a0.w * Uc[3];
    h0 += a1.x * Uc[4] + a1.y * Uc[5] + a1.z * Uc[6] + a1.w * Uc[7];
    h0 += a2.x * Uc[8] + a2.y * Uc[9] + a2.z * Uc[10] + a2.w * Uc[11];
    h0 += a3.x * Uc[12] + a3.y * Uc[13] + a3.z * Uc[14] + a3.w * Uc[15];
    h0 += eav0.x * Ec[0] + eav0.y * Ec[1] + eav0.z * Ec[2] + eav0.w * Ec[3];
    sj += ftanh(h0);
  }

  // agg[k] = sum_j s_j * W2m[j][k] + cnt*b2m[k]  via 4-group LDS transpose
  float W2mT[16];
  #pragma unroll
  for (int q = 0; q < 16; q++) W2mT[q] = W2m[(g * 16 + q) * 16 + kk];
  ldsS[wv][j] = sj;
  float pk = 0.f;
  #pragma unroll
  for (int q = 0; q < 16; q++) pk += ldsS[wv][g * 16 + q] * W2mT[q];
  pk += __shfl_xor(pk, 16, 64);
  pk += __shfl_xor(pk, 32, 64);
  float aggk = pk + (float)(e1 - e0) * b2m[kk];
  ldsA[wv][kk] = aggk;  // 4 lanes/k write identical value

  // node MLP
  float Xc[16], Ac[16];
  #pragma unroll
  for (int i = 0; i < 16; i++) { Xc[i] = W1n[i * 64 + j]; Ac[i] = W1n[(16 + i) * 64 + j]; }
  float tw = W1n[208 * 64 + j];
  float g2 = aug_pre[n * 64 + j] + ti * tw;
  #pragma unroll
  for (int i = 0; i < 16; i++) g2 += xd[i] * Xc[i];
  #pragma unroll
  for (int i = 0; i < 16; i++) g2 += ldsA[wv][i] * Ac[i];
  float h2 = ftanh(g2);

  float W2nT[16];
  #pragma unroll
  for (int q = 0; q < 16; q++) W2nT[q] = W2n[(g * 16 + q) * 16 + kk];
  ldsS[wv][j] = h2;
  float ok = 0.f;
  #pragma unroll
  for (int q = 0; q < 16; q++) ok += ldsS[wv][g * 16 + q] * W2nT[q];
  ok += __shfl_xor(ok, 16, 64);
  ok += __shfl_xor(ok, 32, 64);
  if (j < 16) kout[n * 16 + j] = ok + b2n[j];
}

// ---------------- RK combine (elementwise, float4) ----------------

template <int NK, bool OUT>
__global__ __launch_bounds__(256) void combine_kernel(
    float4* __restrict__ dst, const float4* __restrict__ x,
    const float4* __restrict__ k0, const float4* __restrict__ k1,
    const float4* __restrict__ k2, const float4* __restrict__ k3,
    const float4* __restrict__ k4,
    const float* __restrict__ dts, int u,
    float a0, float a1, float a2, float a3, float a4,
    float4* __restrict__ dout, const int* __restrict__ mask_idx, int m) {
  int i = blockIdx.x * 256 + threadIdx.x;
  if (i >= NN * FF / 4) return;
  float dt = dts[u];
  float4 r = x[i];
  float c;
  float4 v;
  c = dt * a0; v = k0[i];
  r.x += c * v.x; r.y += c * v.y; r.z += c * v.z; r.w += c * v.w;
  if (NK > 1) { c = dt * a1; v = k1[i]; r.x += c * v.x; r.y += c * v.y; r.z += c * v.z; r.w += c * v.w; }
  if (NK > 2) { c = dt * a2; v = k2[i]; r.x += c * v.x; r.y += c * v.y; r.z += c * v.z; r.w += c * v.w; }
  if (NK > 3) { c = dt * a3; v = k3[i]; r.x += c * v.x; r.y += c * v.y; r.z += c * v.z; r.w += c * v.w; }
  if (NK > 4) { c = dt * a4; v = k4[i]; r.x += c * v.x; r.y += c * v.y; r.z += c * v.z; r.w += c * v.w; }
  dst[i] = r;
  if (OUT) {
    #pragma unroll
    for (int rr = 0; rr < 10; rr++)
      if (mask_idx[rr] == m) dout[rr * (NN * FF / 4) + i] = r;
  }
}

// ---------------- host ----------------

extern "C" void kernel_launch(void* const* d_in, const int* in_sizes, int n_in,
                              void* d_out, int out_size, void* d_ws, size_t ws_size,
                              hipStream_t stream) {
  const float* x_hist = (const float*)d_in[0];
  const float* x_mask = (const float*)d_in[1];
  const int* edge_index = (const int*)d_in[2];
  const float* edge_attr = (const float*)d_in[3];
  const float* t = (const float*)d_in[4];
  const int* mask_idx = (const int*)d_in[5];
  const float* W1m = (const float*)d_in[6];
  const float* b1m = (const float*)d_in[7];
  const float* W2m = (const float*)d_in[8];
  const float* b2m = (const float*)d_in[9];
  const float* W1n = (const float*)d_in[10];
  const float* b1n = (const float*)d_in[11];
  const float* W2n = (const float*)d_in[12];
  const float* b2n = (const float*)d_in[13];
  float* out = (float*)d_out;

  size_t off = 0;
  char* wsb = (char*)d_ws;
  auto alloc = [&](size_t bytes) -> void* {
    void* p = (void*)(wsb + off);
    off += (bytes + 255) & ~(size_t)255;
    return p;
  };
  int* row_ptr = (int*)alloc((NN + 1) * sizeof(int));
  int* counts = (int*)alloc(NN * sizeof(int));
  int* src_sorted = (int*)alloc(EE * sizeof(int));
  float* ea_sorted = (float*)alloc((size_t)EE * 4 * sizeof(float));
  float* aug_pre = (float*)alloc((size_t)NN * 64 * sizeof(float));
  float* xA = (float*)alloc((size_t)NN * FF * sizeof(float));
  float* xB = (float*)alloc((size_t)NN * FF * sizeof(float));
  float* xi_t = (float*)alloc((size_t)NN * FF * sizeof(float));
  float* kb[6];
  for (int i = 0; i < 6; i++) kb[i] = (float*)alloc((size_t)NN * FF * sizeof(float));
  float* dts = (float*)alloc(40 * sizeof(float));
  float* tis = (float*)alloc(240 * sizeof(float));

  // CSR build
  hipMemsetAsync(counts, 0, NN * sizeof(int), stream);
  count_kernel<<<(EE + 255) / 256, 256, 0, stream>>>(edge_index, counts);
  scan_kernel<<<1, 1024, 0, stream>>>(counts, row_ptr);
  hipMemsetAsync(counts, 0, NN * sizeof(int), stream);
  fill_kernel<<<(EE + 255) / 256, 256, 0, stream>>>(edge_index, edge_attr, row_ptr, counts,
                                                    src_sorted, ea_sorted);
  augpre_kernel<<<256, 256, 0, stream>>>(x_hist, x_mask, W1n, b1n, aug_pre);
  times_kernel<<<1, 64, 0, stream>>>(t, dts, tis);
  hipMemcpyAsync(xA, x_hist + (size_t)9 * NN * FF, (size_t)NN * FF * sizeof(float),
                 hipMemcpyDeviceToDevice, stream);

  const int CG = (NN * FF / 4 + 255) / 256;  // combine grid
  const int VG = NN / 4;                      // vf grid (4 waves/block)
  float* x = xA;
  float* xn = xB;

  #define VF(XIN, KOUT, TIDX)                                                        \
    vf_kernel<<<VG, 256, 0, stream>>>(XIN, KOUT, row_ptr, src_sorted, ea_sorted,     \
                                      aug_pre, tis, TIDX, W1m, b1m, W2m, b2m, W1n,   \
                                      W2n, b2n)

  for (int u = 0; u < 40; ++u) {
    int tb = u * 6;
    VF(x, kb[0], tb + 0);
    combine_kernel<1, false><<<CG, 256, 0, stream>>>(
        (float4*)xi_t, (const float4*)x, (const float4*)kb[0], nullptr, nullptr, nullptr,
        nullptr, dts, u, 0.2f, 0.f, 0.f, 0.f, 0.f, nullptr, nullptr, -1);
    VF(xi_t, kb[1], tb + 1);
    combine_kernel<2, false><<<CG, 256, 0, stream>>>(
        (float4*)xi_t, (const float4*)x, (const float4*)kb[0], (const float4*)kb[1], nullptr,
        nullptr, nullptr, dts, u, 0.075f, 0.225f, 0.f, 0.f, 0.f, nullptr, nullptr, -1);
    VF(xi_t, kb[2], tb + 2);
    combine_kernel<3, false><<<CG, 256, 0, stream>>>(
        (float4*)xi_t, (const float4*)x, (const float4*)kb[0], (const float4*)kb[1],
        (const float4*)kb[2], nullptr, nullptr, dts, u, (float)(44.0 / 45.0),
        (float)(-56.0 / 15.0), (float)(32.0 / 9.0), 0.f, 0.f, nullptr, nullptr, -1);
    VF(xi_t, kb[3], tb + 3);
    combine_kernel<4, false><<<CG, 256, 0, stream>>>(
        (float4*)xi_t, (const float4*)x, (const float4*)kb[0], (const float4*)kb[1],
        (const float4*)kb[2], (const float4*)kb[3], nullptr, dts, u,
        (float)(19372.0 / 6561.0), (float)(-25360.0 / 2187.0), (float)(64448.0 / 6561.0),
        (float)(-212.0 / 729.0), 0.f, nullptr, nullptr, -1);
    VF(xi_t, kb[4], tb + 4);
    combine_kernel<5, false><<<CG, 256, 0, stream>>>(
        (float4*)xi_t, (const float4*)x, (const float4*)kb[0], (const float4*)kb[1],
        (const float4*)kb[2], (const float4*)kb[3], (const float4*)kb[4], dts, u,
        (float)(9017.0 / 3168.0), (float)(-355.0 / 33.0), (float)(46732.0 / 5247.0),
        (float)(49.0 / 176.0), (float)(-5103.0 / 18656.0), nullptr, nullptr, -1);
    VF(xi_t, kb[5], tb + 5);
    // x_new = x + dt*(B0 k0 + B2 k2 + B3 k3 + B4 k4 + B5 k5)   (B1 = 0)
    int m = ((u & 3) == 3) ? (u >> 2) : -1;
    combine_kernel<5, true><<<CG, 256, 0, stream>>>(
        (float4*)xn, (const float4*)x, (const float4*)kb[0], (const float4*)kb[2],
        (const float4*)kb[3], (const float4*)kb[4], (const float4*)kb[5], dts, u,
        (float)(35.0 / 384.0), (float)(500.0 / 1113.0), (float)(125.0 / 192.0),
        (float)(-2187.0 / 6784.0), (float)(11.0 / 84.0), (float4*)out, mask_idx, m);
    float* tmp = x; x = xn; xn = tmp;
  }
  #undef VF
}